// Round 3
// baseline (1080.822 us; speedup 1.0000x reference)
//
#include <hip/hip_runtime.h>
#include <stdint.h>

typedef float f32x4 __attribute__((ext_vector_type(4)));
typedef short s16x8 __attribute__((ext_vector_type(8)));
typedef short s16x4 __attribute__((ext_vector_type(4)));
typedef unsigned int u32;

#define NSTEPS 499
#define LEN    128
#define HID    512
#define TROW   64000   // 500*128

union frag8 { s16x8 v; u32 u[4]; };
union fvec4 { f32x4 v; float f[4]; };

// Opaque register pin: value becomes asm output -> cannot be rematerialized
// or sunk into the loop; must stay live in VGPRs.
#define PIN_FRAG(fr) asm volatile("" : "+v"((fr).u[0]), "+v"((fr).u[1]), \
                                       "+v"((fr).u[2]), "+v"((fr).u[3]))
#define PIN_F4(fv)   asm volatile("" : "+v"((fv).f[0]), "+v"((fv).f[1]), \
                                       "+v"((fv).f[2]), "+v"((fv).f[3]))

__device__ __forceinline__ short f2bf_rne(float f) {
  union { float f; u32 u; } v; v.f = f;
  u32 r = (v.u + 0x7FFFu + ((v.u >> 16) & 1u)) >> 16;
  return (short)(r & 0xFFFFu);
}

// pack 4 f32 -> 4 bf16 (round-half-away) with 4 adds + 2 v_perm
__device__ __forceinline__ s16x4 pack4(f32x4 v) {
  union { float f; u32 u; } c0, c1, c2, c3;
  c0.f = v[0]; c1.f = v[1]; c2.f = v[2]; c3.f = v[3];
  u32 u0 = c0.u + 0x8000u, u1 = c1.u + 0x8000u;
  u32 u2 = c2.u + 0x8000u, u3 = c3.u + 0x8000u;
  union { u32 x[2]; s16x4 s; } r;
  r.x[0] = __builtin_amdgcn_perm(u1, u0, 0x07060302u);
  r.x[1] = __builtin_amdgcn_perm(u3, u2, 0x07060302u);
  return r.s;
}

// One WG = 256 thr = 4 waves = 1 wave/SIMD owns 16 batch rows for all steps.
//
// vs 531us version (8 waves): the kernel is LDS-read-amplification bound —
// every wave reads ALL of hbf per step (amp = #waves). Halving the wave
// count halves per-CU LDS read traffic while keeping per-SIMD MFMA/VALU
// work identical (1 wave does 2 waves' work). Each wave owns 8 L1 tiles
// (128 rows of h) and 2 L2 tiles (32 rows of x) over full K=512.
// Weights live PINNED in VGPRs (~330 regs/lane, 1 wave/SIMD budget=512).
// Activations go through LDS in frag-linear layout: element (batch m, k)
// at shorts offset ((k>>3)*16 + m)*8 + (k&7).
__global__ __launch_bounds__(256, 1)
void cond_diff_kernel(const float* __restrict__ fd,
                      const float* __restrict__ W1,
                      const float* __restrict__ b1,
                      const float* __restrict__ W2,
                      const float* __restrict__ b2,
                      const float* __restrict__ noise,
                      float* __restrict__ out)
{
  const int tid  = threadIdx.x;
  const int w    = tid >> 6;     // wave 0..3
  const int lane = tid & 63;
  const int q    = lane >> 4;    // quad 0..3
  const int lc   = lane & 15;
  const int bb   = blockIdx.x << 4;

  __shared__ short xbf[16 * 16 * 8];       // x  bf16 frag-linear, 4 KB
  __shared__ short hbf[64 * 16 * 8];       // h  bf16 frag-linear, 16 KB

  // ---- layer1 weight A-frags: 8 tiles/wave. A[m=lc][k=32s+8q+i]=W1[k][j] ----
  frag8 a1[8][4];
#pragma unroll
  for (int t = 0; t < 8; ++t) {
    const int j = 128 * w + 16 * t + lc;
#pragma unroll
    for (int s = 0; s < 4; ++s) {
      s16x8 f;
#pragma unroll
      for (int i = 0; i < 8; ++i)
        f[i] = f2bf_rne(W1[(32 * s + 8 * q + i) * HID + j]);
      a1[t][s].v = f;
      PIN_FRAG(a1[t][s]);
    }
  }
  // ---- layer2 weight A-frags: 2 tiles/wave (2w, 2w+1), FULL K=512 ----
  frag8 a2[2][16];
#pragma unroll
  for (int p = 0; p < 2; ++p) {
#pragma unroll
    for (int s = 0; s < 16; ++s) {
      const int kb = 32 * s + 8 * q;
      s16x8 f;
#pragma unroll
      for (int i = 0; i < 8; ++i)
        f[i] = f2bf_rne(W2[(kb + i) * LEN + 16 * (2 * w + p) + lc]);
      a2[p][s].v = f;
      PIN_FRAG(a2[p][s]);
    }
  }

  // ---- biases in C/D layout (rows j0+r, col lc), PINNED ----
  fvec4 bb1[8], bw1[8];
#pragma unroll
  for (int t = 0; t < 8; ++t) {
    const int j0 = 128 * w + 16 * t + 4 * q;
    bb1[t].v = *(const f32x4*)(b1 + j0);
    bw1[t].v = *(const f32x4*)(W1 + 128 * HID + j0);   // time row of W1
    PIN_F4(bb1[t]); PIN_F4(bw1[t]);
  }
  const int l0a = 32 * w + 4 * q;          // tile 2w   rows
  const int l0b = l0a + 16;                // tile 2w+1 rows
  fvec4 nb2[2];
  {
    f32x4 va = *(const f32x4*)(b2 + l0a);
    f32x4 vb = *(const f32x4*)(b2 + l0b);
#pragma unroll
    for (int r = 0; r < 4; ++r) { nb2[0].f[r] = -0.001f * va[r]; nb2[1].f[r] = -0.001f * vb[r]; }
    PIN_F4(nb2[0]); PIN_F4(nb2[1]);
  }

  // ---- x0 = fd[:, 499, :]; fp32 master state (rows l0+r, col batch=lc) ----
  const int obase = (bb + lc) * TROW;
  f32x4 xmA = *(const f32x4*)(fd + obase + NSTEPS * LEN + l0a);
  f32x4 xmB = *(const f32x4*)(fd + obase + NSTEPS * LEN + l0b);
  *(f32x4*)(out + obase + l0a) = xmA;               // out[:, 0, :] = x0
  *(f32x4*)(out + obase + l0b) = xmB;
  *(s16x4*)(&xbf[((l0a >> 3) * 16 + lc) * 8 + (l0a & 7)]) = pack4(xmA);
  *(s16x4*)(&xbf[((l0b >> 3) * 16 + lc) * 8 + (l0b & 7)]) = pack4(xmB);
  __syncthreads();

  const float DTc = 0.001f;
  const float SD  = 0.031622776601683794f;  // sqrt(DT)
  const float C0  = 0.9995f;                // 1 - 0.5*DT

#pragma unroll 1
  for (int k = 0; k < NSTEPS; ++k) {
    const float tt = DTc * (float)(NSTEPS - k);

    f32x4 epsA = *(const f32x4*)(noise + k * LEN + l0a);  // prefetch
    f32x4 epsB = *(const f32x4*)(noise + k * LEN + l0b);

    // ---- layer 1: h = relu(W1^T x^T + (b1 + t*w1t)) ; bias in acc init ----
    f32x4 acc1[8];
#pragma unroll
    for (int t = 0; t < 8; ++t)
#pragma unroll
      for (int r = 0; r < 4; ++r)
        acc1[t][r] = __builtin_fmaf(tt, bw1[t].f[r], bb1[t].f[r]);
#pragma unroll
    for (int s = 0; s < 4; ++s) {
      const s16x8 bf = *(const s16x8*)(&xbf[((4 * s + q) * 16 + lc) * 8]);
#pragma unroll
      for (int t = 0; t < 8; ++t)
        acc1[t] = __builtin_amdgcn_mfma_f32_16x16x32_bf16(a1[t][s].v, bf, acc1[t], 0, 0, 0);
    }
#pragma unroll
    for (int t = 0; t < 8; ++t) {
      f32x4 h;
#pragma unroll
      for (int r = 0; r < 4; ++r) h[r] = fmaxf(acc1[t][r], 0.f);
      const int jb = 128 * w + 16 * t + 4 * q;
      *(s16x4*)(&hbf[((jb >> 3) * 16 + lc) * 8 + (jb & 7)]) = pack4(h);
    }
    __syncthreads();   // publish h

    // ---- layer 2: 2 tiles, full K; each B-frag feeds both tiles ----
    f32x4 acc2[2][2];
#pragma unroll
    for (int p = 0; p < 2; ++p)
#pragma unroll
      for (int c = 0; c < 2; ++c) acc2[p][c] = (f32x4){0.f, 0.f, 0.f, 0.f};
#pragma unroll
    for (int s = 0; s < 16; ++s) {
      const s16x8 bf = *(const s16x8*)(&hbf[((4 * s + q) * 16 + lc) * 8]);
      acc2[0][s & 1] = __builtin_amdgcn_mfma_f32_16x16x32_bf16(a2[0][s].v, bf, acc2[0][s & 1], 0, 0, 0);
      acc2[1][s & 1] = __builtin_amdgcn_mfma_f32_16x16x32_bf16(a2[1][s].v, bf, acc2[1][s & 1], 0, 0, 0);
    }

    // ---- Euler–Maruyama update (fp32) for both owned row-tiles ----
    f32x4 xnA, xnB;
#pragma unroll
    for (int r = 0; r < 4; ++r) {
      const float scA = acc2[0][0][r] + acc2[0][1][r];
      const float t1A = __builtin_fmaf(SD, epsA[r], nb2[0].f[r]);
      const float t2A = __builtin_fmaf(-DTc, scA, t1A);
      xnA[r] = __builtin_fmaf(C0, xmA[r], t2A);
      const float scB = acc2[1][0][r] + acc2[1][1][r];
      const float t1B = __builtin_fmaf(SD, epsB[r], nb2[1].f[r]);
      const float t2B = __builtin_fmaf(-DTc, scB, t1B);
      xnB[r] = __builtin_fmaf(C0, xmB[r], t2B);
    }
    xmA = xnA; xmB = xnB;
    *(s16x4*)(&xbf[((l0a >> 3) * 16 + lc) * 8 + (l0a & 7)]) = pack4(xnA);
    *(s16x4*)(&xbf[((l0b >> 3) * 16 + lc) * 8 + (l0b & 7)]) = pack4(xnB);
    __syncthreads();   // publish x

    // store AFTER the barrier: drains under next step's layer-1
    const int orow = obase + (NSTEPS - k) * LEN;
    *(f32x4*)(out + orow + l0a) = xnA;
    *(f32x4*)(out + orow + l0b) = xnB;
  }
}

extern "C" void kernel_launch(void* const* d_in, const int* in_sizes, int n_in,
                              void* d_out, int out_size, void* d_ws, size_t ws_size,
                              hipStream_t stream) {
  const float* fd    = (const float*)d_in[0];
  const float* W1    = (const float*)d_in[1];
  const float* b1    = (const float*)d_in[2];
  const float* W2    = (const float*)d_in[3];
  const float* b2    = (const float*)d_in[4];
  const float* noise = (const float*)d_in[5];
  (void)in_sizes; (void)n_in; (void)out_size; (void)d_ws; (void)ws_size;
  cond_diff_kernel<<<dim3(32), dim3(256), 0, stream>>>(fd, W1, b1, W2, b2, noise,
                                                       (float*)d_out);
}

// Round 5
// 647.952 us; speedup vs baseline: 1.6681x; 1.6681x over previous
//
#include <hip/hip_runtime.h>
#include <stdint.h>

typedef float f32x4 __attribute__((ext_vector_type(4)));
typedef int   i32x4 __attribute__((ext_vector_type(4)));
typedef short s16x8 __attribute__((ext_vector_type(8)));
typedef short s16x4 __attribute__((ext_vector_type(4)));
typedef unsigned int u32;
typedef long i64;

#define NSTEPS 499
#define LEN    128
#define HID    512
#define TROW   64000   // 500*128

union frag8 { s16x8 v; u32 u[4]; };
union fragq { i64 l; u32 u[2]; };
union fvec4 { f32x4 v; float f[4]; };

// Opaque register pin: value becomes asm output -> cannot be rematerialized
// or sunk into the loop; must stay live in VGPRs.
#define PIN_FRAG(fr)  asm volatile("" : "+v"((fr).u[0]), "+v"((fr).u[1]), \
                                        "+v"((fr).u[2]), "+v"((fr).u[3]))
#define PIN_FRAGQ(fr) asm volatile("" : "+v"((fr).u[0]), "+v"((fr).u[1]))
#define PIN_F4(fv)    asm volatile("" : "+v"((fv).f[0]), "+v"((fv).f[1]), \
                                        "+v"((fv).f[2]), "+v"((fv).f[3]))

__device__ __forceinline__ short f2bf_rne(float f) {
  union { float f; u32 u; } v; v.f = f;
  u32 r = (v.u + 0x7FFFu + ((v.u >> 16) & 1u)) >> 16;
  return (short)(r & 0xFFFFu);
}

// pack 4 f32 -> 4 bf16 (round-half-away) with 4 adds + 2 v_perm
__device__ __forceinline__ s16x4 pack4(f32x4 v) {
  union { float f; u32 u; } c0, c1, c2, c3;
  c0.f = v[0]; c1.f = v[1]; c2.f = v[2]; c3.f = v[3];
  u32 u0 = c0.u + 0x8000u, u1 = c1.u + 0x8000u;
  u32 u2 = c2.u + 0x8000u, u3 = c3.u + 0x8000u;
  union { u32 x[2]; s16x4 s; } r;
  r.x[0] = __builtin_amdgcn_perm(u1, u0, 0x07060302u);
  r.x[1] = __builtin_amdgcn_perm(u3, u2, 0x07060302u);
  return r.s;
}

// pack 2 f32 -> 2 fp8 e4m3 (RNE, saturating) into low/high word of old.
// HI must be a compile-time constant (builtin requires literal op_sel).
template <bool HI>
__device__ __forceinline__ u32 cvt2_fp8(float a, float b, u32 old) {
  return (u32)__builtin_amdgcn_cvt_pk_fp8_f32(a, b, (int)old, HI);
}

// One WG = 512 thr = 8 waves = 2 waves/SIMD (latency hiding!) owns 16 batch
// rows for all steps. Weights live PINNED in VGPRs. Layer 1 is bf16 MFMA
// (x through LDS as bf16, 4KB). Layer 2 is FP8 e4m3 MFMA: h goes through
// LDS as fp8 (8KB) -> L2's B-frag reads halve (8x ds_read_b128 per wave,
// each read covers k=64 via an interleaved two-frag layout).
// Exact power-of-2 scaling: a1/bb1/bw1 carry x32 (so h' = 32*h from relu
// directly), a2 carries x64 (W2'=64*W2); the score comes out x2048 and the
// update constant is -DT/2048. All scales exact in bf16/fp8 (exponent only).
//
// fp8 LDS layout for h' (bytes): k in [0,512), m = batch col:
//   g = k>>6, kk = k&63:  addr = g*1024 + (((kk>>3)&3)*16 + m)*16
//                                + (kk>>5)*8 + (kk&7)
// -> L2 read: lane (q,m) ds_read_b128 at g*1024 + (q*16+m)*16 yields
//    u[0:1] = B-frag k-chunk [64g,64g+32), u[2:3] = chunk [64g+32,64g+64).
__global__ __launch_bounds__(512, 2)
void cond_diff_kernel(const float* __restrict__ fd,
                      const float* __restrict__ W1,
                      const float* __restrict__ b1,
                      const float* __restrict__ W2,
                      const float* __restrict__ b2,
                      const float* __restrict__ noise,
                      float* __restrict__ out)
{
  const int tid  = threadIdx.x;
  const int w    = tid >> 6;     // wave 0..7
  const int lane = tid & 63;
  const int q    = lane >> 4;    // quad 0..3
  const int lc   = lane & 15;
  const int bb   = blockIdx.x << 4;

  __shared__ short xbf[16 * 16 * 8];   // x bf16 frag-linear, 4 KB
  __shared__ i32x4 hq4[512];           // h fp8, 8 KB (layout above)
  unsigned char* const hqp = (unsigned char*)hq4;

  // ---- layer1 weight A-frags: A[m=lc][k=8q+i] = 32*W1[k][j], PINNED ----
  frag8 a1[4][4];
#pragma unroll
  for (int t = 0; t < 4; ++t) {
    const int j = 64 * w + 16 * t + lc;
#pragma unroll
    for (int s = 0; s < 4; ++s) {
      s16x8 f;
#pragma unroll
      for (int i = 0; i < 8; ++i)
        f[i] = f2bf_rne(32.0f * W1[(32 * s + 8 * q + i) * HID + j]);
      a1[t][s].v = f;
      PIN_FRAG(a1[t][s]);
    }
  }
  // ---- layer2 weight A-frags: own l-tile (w), FULL K=512, fp8(64*W2) ----
  fragq a2[16];
#pragma unroll
  for (int s = 0; s < 16; ++s) {
    const int kb = 32 * s + 8 * q;
    const float* wp = W2 + 16 * w + lc;
    u32 u0 = cvt2_fp8<false>(64.f * wp[(kb + 0) * LEN], 64.f * wp[(kb + 1) * LEN], 0u);
    u0     = cvt2_fp8<true >(64.f * wp[(kb + 2) * LEN], 64.f * wp[(kb + 3) * LEN], u0);
    u32 u1 = cvt2_fp8<false>(64.f * wp[(kb + 4) * LEN], 64.f * wp[(kb + 5) * LEN], 0u);
    u1     = cvt2_fp8<true >(64.f * wp[(kb + 6) * LEN], 64.f * wp[(kb + 7) * LEN], u1);
    a2[s].u[0] = u0; a2[s].u[1] = u1;
    PIN_FRAGQ(a2[s]);
  }

  // ---- biases in C/D layout (rows j0+r, col lc), x32, PINNED ----
  fvec4 bb1[4], bw1[4];
#pragma unroll
  for (int t = 0; t < 4; ++t) {
    const int j0 = 64 * w + 16 * t + 4 * q;
    f32x4 b1v = *(const f32x4*)(b1 + j0);
    f32x4 w1t = *(const f32x4*)(W1 + 128 * HID + j0);   // time row of W1
#pragma unroll
    for (int r = 0; r < 4; ++r) { bb1[t].f[r] = 32.f * b1v[r]; bw1[t].f[r] = 32.f * w1t[r]; }
    PIN_F4(bb1[t]); PIN_F4(bw1[t]);
  }
  const int l0 = 16 * w + 4 * q;           // owned output rows (tile == w)
  fvec4 nb2;
  {
    f32x4 b2v = *(const f32x4*)(b2 + l0);
#pragma unroll
    for (int r = 0; r < 4; ++r) nb2.f[r] = -0.001f * b2v[r];
    PIN_F4(nb2);
  }

  // ---- x0 = fd[:, 499, :]; fp32 master state (rows l0+r, col batch=lc) ----
  const int obase = (bb + lc) * TROW;
  f32x4 xm = *(const f32x4*)(fd + obase + NSTEPS * LEN + l0);
  *(f32x4*)(out + obase + l0) = xm;                 // out[:, 0, :] = x0
  *(s16x4*)(&xbf[((l0 >> 3) * 16 + lc) * 8 + (l0 & 7)]) = pack4(xm);
  __syncthreads();

  const float DTc = 0.001f;
  const float SD  = 0.031622776601683794f;  // sqrt(DT)
  const float C0  = 0.9995f;                // 1 - 0.5*DT
  const float NS  = -0.001f / 2048.0f;      // -DT / (32*64) descale

#pragma unroll 1
  for (int k = 0; k < NSTEPS; ++k) {
    const float tt = DTc * (float)(NSTEPS - k);

    f32x4 eps = *(const f32x4*)(noise + k * LEN + l0);  // prefetch

    // ---- layer 1 (bf16): 32*h = relu(32*(W1^T x^T) + 32*(b1 + t*w1t)) ----
    f32x4 acc1[4];
#pragma unroll
    for (int t = 0; t < 4; ++t)
#pragma unroll
      for (int r = 0; r < 4; ++r)
        acc1[t][r] = __builtin_fmaf(tt, bw1[t].f[r], bb1[t].f[r]);
#pragma unroll
    for (int s = 0; s < 4; ++s) {
      const s16x8 bf = *(const s16x8*)(&xbf[((4 * s + q) * 16 + lc) * 8]);
#pragma unroll
      for (int t = 0; t < 4; ++t)
        acc1[t] = __builtin_amdgcn_mfma_f32_16x16x32_bf16(a1[t][s].v, bf, acc1[t], 0, 0, 0);
    }
    // relu -> fp8 pack -> LDS (4 x b32 writes/lane)
#pragma unroll
    for (int t = 0; t < 4; ++t) {
      f32x4 h;
#pragma unroll
      for (int r = 0; r < 4; ++r) h[r] = fmaxf(acc1[t][r], 0.f);
      u32 hw = cvt2_fp8<false>(h[0], h[1], 0u);
      hw     = cvt2_fp8<true >(h[2], h[3], hw);
      const int kk = 16 * t + 4 * q;                 // k within wave's 64-row group
      *(u32*)(hqp + w * 1024 + (((kk >> 3) & 3) * 16 + lc) * 16
                  + ((kk >> 5) * 8) + (kk & 7)) = hw;
    }
    __syncthreads();   // publish h

    // ---- layer 2 (fp8): own tile, full K; 8 b128 reads -> 16 MFMAs ----
    f32x4 acc2[4];
#pragma unroll
    for (int c = 0; c < 4; ++c) acc2[c] = (f32x4){0.f, 0.f, 0.f, 0.f};
#pragma unroll
    for (int g = 0; g < 8; ++g) {
      const i32x4 rv = *(const i32x4*)(hqp + g * 1024 + (q * 16 + lc) * 16);
      fragq lo, hi;
      lo.u[0] = rv[0]; lo.u[1] = rv[1];
      hi.u[0] = rv[2]; hi.u[1] = rv[3];
      acc2[(2 * g) & 3]     = __builtin_amdgcn_mfma_f32_16x16x32_fp8_fp8(
                                a2[2 * g].l, lo.l, acc2[(2 * g) & 3], 0, 0, 0);
      acc2[(2 * g + 1) & 3] = __builtin_amdgcn_mfma_f32_16x16x32_fp8_fp8(
                                a2[2 * g + 1].l, hi.l, acc2[(2 * g + 1) & 3], 0, 0, 0);
    }

    // ---- Euler–Maruyama update (fp32); score = sc/2048 via NS ----
    f32x4 xn;
#pragma unroll
    for (int r = 0; r < 4; ++r) {
      const float sc = (acc2[0][r] + acc2[1][r]) + (acc2[2][r] + acc2[3][r]);
      const float t1 = __builtin_fmaf(SD, eps[r], nb2.f[r]);
      const float t2 = __builtin_fmaf(NS, sc, t1);
      xn[r] = __builtin_fmaf(C0, xm[r], t2);
    }
    xm = xn;
    *(s16x4*)(&xbf[((l0 >> 3) * 16 + lc) * 8 + (l0 & 7)]) = pack4(xn);
    __syncthreads();   // publish x

    // store AFTER the barrier: drains under next step's layer-1
    *(f32x4*)(out + obase + (NSTEPS - k) * LEN + l0) = xn;
  }
}

extern "C" void kernel_launch(void* const* d_in, const int* in_sizes, int n_in,
                              void* d_out, int out_size, void* d_ws, size_t ws_size,
                              hipStream_t stream) {
  const float* fd    = (const float*)d_in[0];
  const float* W1    = (const float*)d_in[1];
  const float* b1    = (const float*)d_in[2];
  const float* W2    = (const float*)d_in[3];
  const float* b2    = (const float*)d_in[4];
  const float* noise = (const float*)d_in[5];
  (void)in_sizes; (void)n_in; (void)out_size; (void)d_ws; (void)ws_size;
  cond_diff_kernel<<<dim3(32), dim3(512), 0, stream>>>(fd, W1, b1, W2, b2, noise,
                                                       (float*)d_out);
}

// Round 6
// 637.942 us; speedup vs baseline: 1.6942x; 1.0157x over previous
//
#include <hip/hip_runtime.h>
#include <stdint.h>

typedef float f32x4 __attribute__((ext_vector_type(4)));
typedef int   i32x4 __attribute__((ext_vector_type(4)));
typedef short s16x8 __attribute__((ext_vector_type(8)));
typedef short s16x4 __attribute__((ext_vector_type(4)));
typedef unsigned int u32;
typedef long i64;

#define NSTEPS 499
#define LEN    128
#define HID    512
#define TROW   64000   // 500*128

union frag8 { s16x8 v; u32 u[4]; };
union fragq { i64 l; u32 u[2]; };
union fvec4 { f32x4 v; float f[4]; };

// Opaque register pin: value becomes asm output -> cannot be rematerialized
// or sunk into the loop; must stay live in VGPRs.
#define PIN_FRAG(fr)  asm volatile("" : "+v"((fr).u[0]), "+v"((fr).u[1]), \
                                        "+v"((fr).u[2]), "+v"((fr).u[3]))
#define PIN_FRAGQ(fr) asm volatile("" : "+v"((fr).u[0]), "+v"((fr).u[1]))
#define PIN_F4(fv)    asm volatile("" : "+v"((fv).f[0]), "+v"((fv).f[1]), \
                                        "+v"((fv).f[2]), "+v"((fv).f[3]))

// Barrier with LDS-only drain: skips the vmcnt(0) that __syncthreads()
// forces (out-store is never read by another wave; eps loads are consumed
// with compiler-inserted waits). Memory clobber orders all LDS ops.
#define BAR_LGKM() asm volatile("s_waitcnt lgkmcnt(0)\ns_barrier" ::: "memory")

__device__ __forceinline__ short f2bf_rne(float f) {
  union { float f; u32 u; } v; v.f = f;
  u32 r = (v.u + 0x7FFFu + ((v.u >> 16) & 1u)) >> 16;
  return (short)(r & 0xFFFFu);
}

// pack 4 f32 -> 4 bf16 (round-half-away) with 4 adds + 2 v_perm
__device__ __forceinline__ s16x4 pack4(f32x4 v) {
  union { float f; u32 u; } c0, c1, c2, c3;
  c0.f = v[0]; c1.f = v[1]; c2.f = v[2]; c3.f = v[3];
  u32 u0 = c0.u + 0x8000u, u1 = c1.u + 0x8000u;
  u32 u2 = c2.u + 0x8000u, u3 = c3.u + 0x8000u;
  union { u32 x[2]; s16x4 s; } r;
  r.x[0] = __builtin_amdgcn_perm(u1, u0, 0x07060302u);
  r.x[1] = __builtin_amdgcn_perm(u3, u2, 0x07060302u);
  return r.s;
}

// pack 2 f32 -> 2 fp8 e4m3 (RNE, saturating) into low/high word of old.
// HI must be a compile-time constant (builtin requires literal op_sel).
template <bool HI>
__device__ __forceinline__ u32 cvt2_fp8(float a, float b, u32 old) {
  return (u32)__builtin_amdgcn_cvt_pk_fp8_f32(a, b, (int)old, HI);
}

// One WG = 512 thr = 8 waves = 2 waves/SIMD owns 16 batch rows for all steps.
// Layer 1 bf16 MFMA (x via LDS bf16, 4KB); layer 2 fp8 e4m3 MFMA (h via LDS
// fp8, 8KB; 8x ds_read_b128/wave, each covering k=64 via dual-frag layout).
// Exact power-of-2 scaling: a1/bb1/bw1 x32, a2 x64, descale -DT/2048.
//
// vs 470us version:
//  - raw s_barrier with lgkm-only drain (no vmcnt(0) at either barrier)
//  - wave w issues its OWN hbf slice read (g=w) BEFORE the h-barrier (it
//    wrote that block itself; only its own lgkm flush is needed) -> read
//    completes during barrier arbitration
//  - a2 slots rotated: slot j <-> g=(w+j)&7, rotation applied at weight
//    load (runtime address, compile-time register index) -> skewed sweep
//    over hbf spreads the post-barrier read burst across waves
//
// fp8 LDS layout for h' (bytes): k in [0,512), m = batch col:
//   g = k>>6, kk = k&63:  addr = g*1024 + (((kk>>3)&3)*16 + m)*16
//                                + (kk>>5)*8 + (kk&7)
// -> read: lane (q,m) b128 at g*1024 + (q*16+m)*16: u[0:1]=k [64g+8q,+8),
//    u[2:3]=k [64g+32+8q,+8).
__global__ __launch_bounds__(512, 2)
void cond_diff_kernel(const float* __restrict__ fd,
                      const float* __restrict__ W1,
                      const float* __restrict__ b1,
                      const float* __restrict__ W2,
                      const float* __restrict__ b2,
                      const float* __restrict__ noise,
                      float* __restrict__ out)
{
  const int tid  = threadIdx.x;
  const int w    = tid >> 6;     // wave 0..7
  const int lane = tid & 63;
  const int q    = lane >> 4;    // quad 0..3
  const int lc   = lane & 15;
  const int bb   = blockIdx.x << 4;

  __shared__ short xbf[16 * 16 * 8];   // x bf16 frag-linear, 4 KB
  __shared__ i32x4 hq4[512];           // h fp8, 8 KB (layout above)
  unsigned char* const hqp = (unsigned char*)hq4;

  // ---- layer1 weight A-frags: A[m=lc][k=8q+i] = 32*W1[k][j], PINNED ----
  frag8 a1[4][4];
#pragma unroll
  for (int t = 0; t < 4; ++t) {
    const int j = 64 * w + 16 * t + lc;
#pragma unroll
    for (int s = 0; s < 4; ++s) {
      s16x8 f;
#pragma unroll
      for (int i = 0; i < 8; ++i)
        f[i] = f2bf_rne(32.0f * W1[(32 * s + 8 * q + i) * HID + j]);
      a1[t][s].v = f;
      PIN_FRAG(a1[t][s]);
    }
  }
  // ---- layer2 weight A-frags: own l-tile (w), full K, fp8(64*W2), slot
  //      pair j covers k-block g=(w+j)&7 (rotated processing order) ----
  fragq a2[16];
#pragma unroll
  for (int j = 0; j < 8; ++j) {
    const int g = (w + j) & 7;
#pragma unroll
    for (int c = 0; c < 2; ++c) {
      const int kb = 64 * g + 32 * c + 8 * q;
      const float* wp = W2 + 16 * w + lc;
      u32 u0 = cvt2_fp8<false>(64.f * wp[(kb + 0) * LEN], 64.f * wp[(kb + 1) * LEN], 0u);
      u0     = cvt2_fp8<true >(64.f * wp[(kb + 2) * LEN], 64.f * wp[(kb + 3) * LEN], u0);
      u32 u1 = cvt2_fp8<false>(64.f * wp[(kb + 4) * LEN], 64.f * wp[(kb + 5) * LEN], 0u);
      u1     = cvt2_fp8<true >(64.f * wp[(kb + 6) * LEN], 64.f * wp[(kb + 7) * LEN], u1);
      a2[2 * j + c].u[0] = u0; a2[2 * j + c].u[1] = u1;
      PIN_FRAGQ(a2[2 * j + c]);
    }
  }

  // ---- biases in C/D layout (rows j0+r, col lc), x32, PINNED ----
  fvec4 bb1[4], bw1[4];
#pragma unroll
  for (int t = 0; t < 4; ++t) {
    const int j0 = 64 * w + 16 * t + 4 * q;
    f32x4 b1v = *(const f32x4*)(b1 + j0);
    f32x4 w1t = *(const f32x4*)(W1 + 128 * HID + j0);   // time row of W1
#pragma unroll
    for (int r = 0; r < 4; ++r) { bb1[t].f[r] = 32.f * b1v[r]; bw1[t].f[r] = 32.f * w1t[r]; }
    PIN_F4(bb1[t]); PIN_F4(bw1[t]);
  }
  const int l0 = 16 * w + 4 * q;           // owned output rows (tile == w)
  fvec4 nb2;
  {
    f32x4 b2v = *(const f32x4*)(b2 + l0);
#pragma unroll
    for (int r = 0; r < 4; ++r) nb2.f[r] = -0.001f * b2v[r];
    PIN_F4(nb2);
  }

  // ---- x0 = fd[:, 499, :]; fp32 master state (rows l0+r, col batch=lc) ----
  const int obase = (bb + lc) * TROW;
  f32x4 xm = *(const f32x4*)(fd + obase + NSTEPS * LEN + l0);
  *(f32x4*)(out + obase + l0) = xm;                 // out[:, 0, :] = x0
  *(s16x4*)(&xbf[((l0 >> 3) * 16 + lc) * 8 + (l0 & 7)]) = pack4(xm);
  __syncthreads();

  const float DTc = 0.001f;
  const float SD  = 0.031622776601683794f;  // sqrt(DT)
  const float C0  = 0.9995f;                // 1 - 0.5*DT
  const float NS  = -0.001f / 2048.0f;      // -DT / (32*64) descale

#pragma unroll 1
  for (int k = 0; k < NSTEPS; ++k) {
    const float tt = DTc * (float)(NSTEPS - k);

    f32x4 eps = *(const f32x4*)(noise + k * LEN + l0);  // prefetch

    // ---- layer 1 (bf16): 32*h = relu(32*(W1^T x^T) + 32*(b1 + t*w1t)) ----
    f32x4 acc1[4];
#pragma unroll
    for (int t = 0; t < 4; ++t)
#pragma unroll
      for (int r = 0; r < 4; ++r)
        acc1[t][r] = __builtin_fmaf(tt, bw1[t].f[r], bb1[t].f[r]);
#pragma unroll
    for (int s = 0; s < 4; ++s) {
      const s16x8 bf = *(const s16x8*)(&xbf[((4 * s + q) * 16 + lc) * 8]);
#pragma unroll
      for (int t = 0; t < 4; ++t)
        acc1[t] = __builtin_amdgcn_mfma_f32_16x16x32_bf16(a1[t][s].v, bf, acc1[t], 0, 0, 0);
    }
    // relu -> fp8 pack -> LDS (4 x b32 writes/lane)
#pragma unroll
    for (int t = 0; t < 4; ++t) {
      f32x4 h;
#pragma unroll
      for (int r = 0; r < 4; ++r) h[r] = fmaxf(acc1[t][r], 0.f);
      u32 hw = cvt2_fp8<false>(h[0], h[1], 0u);
      hw     = cvt2_fp8<true >(h[2], h[3], hw);
      const int kk = 16 * t + 4 * q;                 // k within wave's 64-row group
      *(u32*)(hqp + w * 1024 + (((kk >> 3) & 3) * 16 + lc) * 16
                  + ((kk >> 5) * 8) + (kk & 7)) = hw;
    }

    // flush own h-writes, then issue own-slice read BEFORE the barrier
    // (block w was written by this wave only) - it completes during
    // barrier arbitration.
    asm volatile("s_waitcnt lgkmcnt(0)" ::: "memory");
    const i32x4 rv0 = *(const i32x4*)(hqp + w * 1024 + (q * 16 + lc) * 16);
    asm volatile("s_barrier" ::: "memory");   // publish h (lgkm already 0 for writes)

    // ---- layer 2 (fp8): own tile, full K; rotated slot order, j=0=own ----
    f32x4 acc2[4];
#pragma unroll
    for (int c = 0; c < 4; ++c) acc2[c] = (f32x4){0.f, 0.f, 0.f, 0.f};
    {
      fragq lo, hi;
      lo.u[0] = rv0[0]; lo.u[1] = rv0[1];
      hi.u[0] = rv0[2]; hi.u[1] = rv0[3];
      acc2[0] = __builtin_amdgcn_mfma_f32_16x16x32_fp8_fp8(a2[0].l, lo.l, acc2[0], 0, 0, 0);
      acc2[1] = __builtin_amdgcn_mfma_f32_16x16x32_fp8_fp8(a2[1].l, hi.l, acc2[1], 0, 0, 0);
    }
#pragma unroll
    for (int j = 1; j < 8; ++j) {
      const int g = (w + j) & 7;
      const i32x4 rv = *(const i32x4*)(hqp + g * 1024 + (q * 16 + lc) * 16);
      fragq lo, hi;
      lo.u[0] = rv[0]; lo.u[1] = rv[1];
      hi.u[0] = rv[2]; hi.u[1] = rv[3];
      acc2[(2 * j) & 3]     = __builtin_amdgcn_mfma_f32_16x16x32_fp8_fp8(
                                a2[2 * j].l, lo.l, acc2[(2 * j) & 3], 0, 0, 0);
      acc2[(2 * j + 1) & 3] = __builtin_amdgcn_mfma_f32_16x16x32_fp8_fp8(
                                a2[2 * j + 1].l, hi.l, acc2[(2 * j + 1) & 3], 0, 0, 0);
    }

    // ---- Euler–Maruyama update (fp32); score = sc/2048 via NS ----
    f32x4 xn;
#pragma unroll
    for (int r = 0; r < 4; ++r) {
      const float sc = (acc2[0][r] + acc2[1][r]) + (acc2[2][r] + acc2[3][r]);
      const float t1 = __builtin_fmaf(SD, eps[r], nb2.f[r]);
      const float t2 = __builtin_fmaf(NS, sc, t1);
      xn[r] = __builtin_fmaf(C0, xm[r], t2);
    }
    xm = xn;
    *(s16x4*)(&xbf[((l0 >> 3) * 16 + lc) * 8 + (l0 & 7)]) = pack4(xn);
    BAR_LGKM();        // publish x (also covers WAR on this wave's L2 reads)

    // store AFTER the barrier: drains under next step's layer-1
    *(f32x4*)(out + obase + (NSTEPS - k) * LEN + l0) = xn;
  }
}

extern "C" void kernel_launch(void* const* d_in, const int* in_sizes, int n_in,
                              void* d_out, int out_size, void* d_ws, size_t ws_size,
                              hipStream_t stream) {
  const float* fd    = (const float*)d_in[0];
  const float* W1    = (const float*)d_in[1];
  const float* b1    = (const float*)d_in[2];
  const float* W2    = (const float*)d_in[3];
  const float* b2    = (const float*)d_in[4];
  const float* noise = (const float*)d_in[5];
  (void)in_sizes; (void)n_in; (void)out_size; (void)d_ws; (void)ws_size;
  cond_diff_kernel<<<dim3(32), dim3(512), 0, stream>>>(fd, W1, b1, W2, b2, noise,
                                                       (float*)d_out);
}

// Round 7
// 604.863 us; speedup vs baseline: 1.7869x; 1.0547x over previous
//
#include <hip/hip_runtime.h>
#include <stdint.h>

typedef float f32x4 __attribute__((ext_vector_type(4)));
typedef int   i32x4 __attribute__((ext_vector_type(4)));
typedef int   i32x8 __attribute__((ext_vector_type(8)));
typedef short s16x8 __attribute__((ext_vector_type(8)));
typedef short s16x4 __attribute__((ext_vector_type(4)));
typedef unsigned int u32;

#define NSTEPS 499
#define LEN    128
#define HID    512
#define TROW   64000   // 500*128

union frag8  { s16x8 v; u32 u[4]; };
union frag32 { i32x8 v; u32 u[8]; i32x4 h[2]; };
union fvec4  { f32x4 v; float f[4]; };

// Opaque register pin: value becomes asm output -> cannot be rematerialized
// or sunk into the loop; must stay live in VGPRs.
#define PIN_FRAG(fr)  asm volatile("" : "+v"((fr).u[0]), "+v"((fr).u[1]), \
                                        "+v"((fr).u[2]), "+v"((fr).u[3]))
#define PIN_FRAG32(fr) asm volatile("" : "+v"((fr).u[0]), "+v"((fr).u[1]), \
                                         "+v"((fr).u[2]), "+v"((fr).u[3]), \
                                         "+v"((fr).u[4]), "+v"((fr).u[5]), \
                                         "+v"((fr).u[6]), "+v"((fr).u[7]))
#define PIN_F4(fv)    asm volatile("" : "+v"((fv).f[0]), "+v"((fv).f[1]), \
                                        "+v"((fv).f[2]), "+v"((fv).f[3]))

__device__ __forceinline__ short f2bf_rne(float f) {
  union { float f; u32 u; } v; v.f = f;
  u32 r = (v.u + 0x7FFFu + ((v.u >> 16) & 1u)) >> 16;
  return (short)(r & 0xFFFFu);
}

// pack 4 f32 -> 4 bf16 (round-half-away) with 4 adds + 2 v_perm
__device__ __forceinline__ s16x4 pack4(f32x4 v) {
  union { float f; u32 u; } c0, c1, c2, c3;
  c0.f = v[0]; c1.f = v[1]; c2.f = v[2]; c3.f = v[3];
  u32 u0 = c0.u + 0x8000u, u1 = c1.u + 0x8000u;
  u32 u2 = c2.u + 0x8000u, u3 = c3.u + 0x8000u;
  union { u32 x[2]; s16x4 s; } r;
  r.x[0] = __builtin_amdgcn_perm(u1, u0, 0x07060302u);
  r.x[1] = __builtin_amdgcn_perm(u3, u2, 0x07060302u);
  return r.s;
}

// pack 2 f32 -> 2 fp8 e4m3 (RNE, saturating) into low/high word of old.
// HI must be a compile-time constant (builtin requires literal op_sel).
template <bool HI>
__device__ __forceinline__ u32 cvt2_fp8(float a, float b, u32 old) {
  return (u32)__builtin_amdgcn_cvt_pk_fp8_f32(a, b, (int)old, HI);
}

// One WG = 512 thr = 8 waves = 2 waves/SIMD owns 16 batch rows for all steps.
// Layer 1 bf16 MFMA (x via LDS bf16, 4KB); layer 2 MX-scaled fp8 MFMA
// (mfma_scale_f32_16x16x128_f8f6f4, unit e8m0 scales = numerically exact):
// 4 MFMAs/wave instead of 16 at 2x the fp8 rate -> L2 MFMA-pipe time /2.2
// and dependency chain 16 -> 4. h via LDS fp8, 8KB; 8x ds_read_b128/wave.
// K-slot safety: k is the reduction dim and A/B lane layouts are symmetric
// for 16x16 shapes, so packing BOTH operands with the same self-chosen
// k-slot order is correct independent of the HW's internal k permutation.
// Exact power-of-2 scaling: a1/bb1/bw1 x32, a2 x64, descale -DT/2048.
//
// fp8 LDS layout for h' (bytes): k in [0,512), m = batch col:
//   g = k>>6, kk = k&63:  addr = g*1024 + (((kk>>3)&3)*16 + m)*16
//                                + (kk>>5)*8 + (kk&7)
// -> read: lane (q,m) b128 at g*1024 + (q*16+m)*16: words 0,1 = k-chunk
//    [64g+8q,+8), words 2,3 = [64g+32+8q,+8).  B-frag f (K=128) = reads
//    g=2f,2f+1 concatenated; A-frag f = W2 k-chunks [128f + {0,32,64,96}
//    + 8q, +8) in the same slot order.
__global__ __launch_bounds__(512, 2)
void cond_diff_kernel(const float* __restrict__ fd,
                      const float* __restrict__ W1,
                      const float* __restrict__ b1,
                      const float* __restrict__ W2,
                      const float* __restrict__ b2,
                      const float* __restrict__ noise,
                      float* __restrict__ out)
{
  const int tid  = threadIdx.x;
  const int w    = tid >> 6;     // wave 0..7
  const int lane = tid & 63;
  const int q    = lane >> 4;    // quad 0..3
  const int lc   = lane & 15;
  const int bb   = blockIdx.x << 4;

  __shared__ short xbf[16 * 16 * 8];   // x bf16 frag-linear, 4 KB
  __shared__ i32x4 hq4[512];           // h fp8, 8 KB (layout above)
  unsigned char* const hqp = (unsigned char*)hq4;

  // ---- layer1 weight A-frags: A[m=lc][k=8q+i] = 32*W1[k][j], PINNED ----
  frag8 a1[4][4];
#pragma unroll
  for (int t = 0; t < 4; ++t) {
    const int j = 64 * w + 16 * t + lc;
#pragma unroll
    for (int s = 0; s < 4; ++s) {
      s16x8 f;
#pragma unroll
      for (int i = 0; i < 8; ++i)
        f[i] = f2bf_rne(32.0f * W1[(32 * s + 8 * q + i) * HID + j]);
      a1[t][s].v = f;
      PIN_FRAG(a1[t][s]);
    }
  }
  // ---- layer2 weight A-frags: own l-tile (w), full K, fp8(64*W2).
  //      a2s[f] covers k=[128f,128f+128): u-pair s4 = k [128f+32*s4+8q,+8) ----
  frag32 a2s[4];
#pragma unroll
  for (int f = 0; f < 4; ++f) {
#pragma unroll
    for (int s4 = 0; s4 < 4; ++s4) {
      const int kb = 128 * f + 32 * s4 + 8 * q;
      const float* wp = W2 + 16 * w + lc;
      u32 u0 = cvt2_fp8<false>(64.f * wp[(kb + 0) * LEN], 64.f * wp[(kb + 1) * LEN], 0u);
      u0     = cvt2_fp8<true >(64.f * wp[(kb + 2) * LEN], 64.f * wp[(kb + 3) * LEN], u0);
      u32 u1 = cvt2_fp8<false>(64.f * wp[(kb + 4) * LEN], 64.f * wp[(kb + 5) * LEN], 0u);
      u1     = cvt2_fp8<true >(64.f * wp[(kb + 6) * LEN], 64.f * wp[(kb + 7) * LEN], u1);
      a2s[f].u[2 * s4]     = u0;
      a2s[f].u[2 * s4 + 1] = u1;
    }
    PIN_FRAG32(a2s[f]);
  }

  // ---- biases in C/D layout (rows j0+r, col lc), x32, PINNED ----
  fvec4 bb1[4], bw1[4];
#pragma unroll
  for (int t = 0; t < 4; ++t) {
    const int j0 = 64 * w + 16 * t + 4 * q;
    f32x4 b1v = *(const f32x4*)(b1 + j0);
    f32x4 w1t = *(const f32x4*)(W1 + 128 * HID + j0);   // time row of W1
#pragma unroll
    for (int r = 0; r < 4; ++r) { bb1[t].f[r] = 32.f * b1v[r]; bw1[t].f[r] = 32.f * w1t[r]; }
    PIN_F4(bb1[t]); PIN_F4(bw1[t]);
  }
  const int l0 = 16 * w + 4 * q;           // owned output rows (tile == w)
  fvec4 nb2;
  {
    f32x4 b2v = *(const f32x4*)(b2 + l0);
#pragma unroll
    for (int r = 0; r < 4; ++r) nb2.f[r] = -0.001f * b2v[r];
    PIN_F4(nb2);
  }

  // ---- x0 = fd[:, 499, :]; fp32 master state (rows l0+r, col batch=lc) ----
  const int obase = (bb + lc) * TROW;
  f32x4 xm = *(const f32x4*)(fd + obase + NSTEPS * LEN + l0);
  *(f32x4*)(out + obase + l0) = xm;                 // out[:, 0, :] = x0
  *(s16x4*)(&xbf[((l0 >> 3) * 16 + lc) * 8 + (l0 & 7)]) = pack4(xm);
  __syncthreads();

  const float DTc = 0.001f;
  const float SD  = 0.031622776601683794f;  // sqrt(DT)
  const float C0  = 0.9995f;                // 1 - 0.5*DT
  const float NS  = -0.001f / 2048.0f;      // -DT / (32*64) descale
  const int   SC1 = 0x7F7F7F7F;             // e8m0 unit scales (2^0) x4 blocks

#pragma unroll 1
  for (int k = 0; k < NSTEPS; ++k) {
    const float tt = DTc * (float)(NSTEPS - k);

    f32x4 eps = *(const f32x4*)(noise + k * LEN + l0);  // prefetch

    // ---- layer 1 (bf16): 32*h = relu(32*(W1^T x^T) + 32*(b1 + t*w1t)) ----
    f32x4 acc1[4];
#pragma unroll
    for (int t = 0; t < 4; ++t)
#pragma unroll
      for (int r = 0; r < 4; ++r)
        acc1[t][r] = __builtin_fmaf(tt, bw1[t].f[r], bb1[t].f[r]);
#pragma unroll
    for (int s = 0; s < 4; ++s) {
      const s16x8 bf = *(const s16x8*)(&xbf[((4 * s + q) * 16 + lc) * 8]);
#pragma unroll
      for (int t = 0; t < 4; ++t)
        acc1[t] = __builtin_amdgcn_mfma_f32_16x16x32_bf16(a1[t][s].v, bf, acc1[t], 0, 0, 0);
    }
    // relu -> fp8 pack -> LDS (4 x b32 writes/lane)
#pragma unroll
    for (int t = 0; t < 4; ++t) {
      f32x4 h;
#pragma unroll
      for (int r = 0; r < 4; ++r) h[r] = fmaxf(acc1[t][r], 0.f);
      u32 hw = cvt2_fp8<false>(h[0], h[1], 0u);
      hw     = cvt2_fp8<true >(h[2], h[3], hw);
      const int kk = 16 * t + 4 * q;                 // k within wave's 64-row group
      *(u32*)(hqp + w * 1024 + (((kk >> 3) & 3) * 16 + lc) * 16
                  + ((kk >> 5) * 8) + (kk & 7)) = hw;
    }
    __syncthreads();   // publish h

    // ---- layer 2 (MX fp8, K=128): own tile; 2 reads + 1 scaled MFMA x4 ----
    f32x4 acc2[2];
    acc2[0] = (f32x4){0.f, 0.f, 0.f, 0.f};
    acc2[1] = (f32x4){0.f, 0.f, 0.f, 0.f};
#pragma unroll
    for (int f = 0; f < 4; ++f) {
      frag32 bfr;
      bfr.h[0] = *(const i32x4*)(hqp + (2 * f) * 1024 + (q * 16 + lc) * 16);
      bfr.h[1] = *(const i32x4*)(hqp + (2 * f + 1) * 1024 + (q * 16 + lc) * 16);
      acc2[f & 1] = __builtin_amdgcn_mfma_scale_f32_16x16x128_f8f6f4(
                      a2s[f].v, bfr.v, acc2[f & 1],
                      0 /*cbsz: A=fp8*/, 0 /*blgp: B=fp8*/,
                      0, SC1, 0, SC1);
    }

    // ---- Euler–Maruyama update (fp32); score = sc/2048 via NS ----
    f32x4 xn;
#pragma unroll
    for (int r = 0; r < 4; ++r) {
      const float sc = acc2[0][r] + acc2[1][r];
      const float t1 = __builtin_fmaf(SD, eps[r], nb2.f[r]);
      const float t2 = __builtin_fmaf(NS, sc, t1);
      xn[r] = __builtin_fmaf(C0, xm[r], t2);
    }
    xm = xn;
    *(s16x4*)(&xbf[((l0 >> 3) * 16 + lc) * 8 + (l0 & 7)]) = pack4(xn);
    __syncthreads();   // publish x

    // store AFTER the barrier: drains under next step's layer-1
    *(f32x4*)(out + obase + (NSTEPS - k) * LEN + l0) = xn;
  }
}

extern "C" void kernel_launch(void* const* d_in, const int* in_sizes, int n_in,
                              void* d_out, int out_size, void* d_ws, size_t ws_size,
                              hipStream_t stream) {
  const float* fd    = (const float*)d_in[0];
  const float* W1    = (const float*)d_in[1];
  const float* b1    = (const float*)d_in[2];
  const float* W2    = (const float*)d_in[3];
  const float* b2    = (const float*)d_in[4];
  const float* noise = (const float*)d_in[5];
  (void)in_sizes; (void)n_in; (void)out_size; (void)d_ws; (void)ws_size;
  cond_diff_kernel<<<dim3(32), dim3(512), 0, stream>>>(fd, W1, b1, W2, b2, noise,
                                                       (float*)d_out);
}

// Round 8
// 555.495 us; speedup vs baseline: 1.9457x; 1.0889x over previous
//
#include <hip/hip_runtime.h>
#include <stdint.h>

typedef float f32x4 __attribute__((ext_vector_type(4)));
typedef int   i32x4 __attribute__((ext_vector_type(4)));
typedef int   i32x8 __attribute__((ext_vector_type(8)));
typedef short s16x8 __attribute__((ext_vector_type(8)));
typedef unsigned int u32;

#define NSTEPS 499
#define LEN    128
#define HID    512
#define TROW   64000   // 500*128

union frag32 { i32x8 v; u32 u[8]; i32x4 h[2]; };
union fvec4  { f32x4 v; float f[4]; };

// Opaque register pin: value becomes asm output -> cannot be rematerialized
// or sunk into the loop; must stay live in VGPRs/AGPRs.
#define PIN_FRAG32(fr) asm volatile("" : "+v"((fr).u[0]), "+v"((fr).u[1]), \
                                         "+v"((fr).u[2]), "+v"((fr).u[3]), \
                                         "+v"((fr).u[4]), "+v"((fr).u[5]), \
                                         "+v"((fr).u[6]), "+v"((fr).u[7]))
#define PIN_F4(fv)    asm volatile("" : "+v"((fv).f[0]), "+v"((fv).f[1]), \
                                        "+v"((fv).f[2]), "+v"((fv).f[3]))

// pack 2 f32 -> 2 fp8 e4m3 (RNE, saturating) into low/high word of old.
// HI must be a compile-time constant (builtin requires literal op_sel).
template <bool HI>
__device__ __forceinline__ u32 cvt2_fp8(float a, float b, u32 old) {
  return (u32)__builtin_amdgcn_cvt_pk_fp8_f32(a, b, (int)old, HI);
}

// One WG = 512 thr = 8 waves = 2 waves/SIMD owns 16 batch rows for all steps.
// BOTH layers are MX-scaled fp8 MFMA (mfma_scale_f32_16x16x128_f8f6f4 with
// unit e8m0 scales): L1 = 4 MFMAs/wave (K=128 = x-dim in ONE instruction per
// l-tile), L2 = 4 MFMAs/wave (K=512 in 4 frags). MFMA-pipe time per CU-step
// ~900 -> ~550 cy; L1 LDS reads halve (2 b128/wave).
// Master state x stays fp32 in registers; fp8 is only the MFMA input path
// (score enters the update x DT=0.001, heavily damped).
// Exact power-of-2 scaling: a1 x32 (h'=32h from relu directly), a2 x64,
// descale -DT/2048. All scales exponent-only = exact.
//
// Uniform fp8 LDS layout (both x and h), 16B-granular:
//   element (k, m) at byte (( (k>>4)*16 + m )*16 + (k&15))
// Writes: lane (w,q,lc) owns 4 consecutive k at base 16*w'+4q -> one u32 at
//   w'*256 + lc*16 + 4q: per-wave lane-linear 256B burst, conflict-free.
// Reads: lane (q,m) takes k-chunk [32q+base, +32) as two b128 at
//   q*512 + m*16 (+256): bank = (m&7)*4.. -> 8 lanes share a 4-bank group,
//   32B/bank = structural minimum, conflict-free.
// K-slot consistency: A-frags are packed from global with the SAME k-order
// (k = 32q + (i>>2)*16 + (i&3)*4 + byte), so the per-lane k permutation
// cancels in the dot product (reduction dim).
__global__ __launch_bounds__(512, 2)
void cond_diff_kernel(const float* __restrict__ fd,
                      const float* __restrict__ W1,
                      const float* __restrict__ b1,
                      const float* __restrict__ W2,
                      const float* __restrict__ b2,
                      const float* __restrict__ noise,
                      float* __restrict__ out)
{
  const int tid  = threadIdx.x;
  const int w    = tid >> 6;     // wave 0..7
  const int lane = tid & 63;
  const int q    = lane >> 4;    // quad 0..3
  const int lc   = lane & 15;
  const int bb   = blockIdx.x << 4;

  __shared__ u32 xq[512];        // x fp8, 2 KB: (k>>4, m) 16B slots
  __shared__ u32 hq[2048];       // h fp8, 8 KB: (k>>4, m) 16B slots
  unsigned char* const xqp = (unsigned char*)xq;
  unsigned char* const hqp = (unsigned char*)hq;

  // ---- layer1 A-frags: fp8(32*W1), rows j=64w+16t+lc, k-order as B ----
  frag32 a1s[4];
#pragma unroll
  for (int t = 0; t < 4; ++t) {
    const int j = 64 * w + 16 * t + lc;
#pragma unroll
    for (int i = 0; i < 8; ++i) {
      const int kb = 32 * q + (i >> 2) * 16 + (i & 3) * 4;
      u32 u0 = cvt2_fp8<false>(32.f * W1[(kb + 0) * HID + j],
                               32.f * W1[(kb + 1) * HID + j], 0u);
      u0     = cvt2_fp8<true >(32.f * W1[(kb + 2) * HID + j],
                               32.f * W1[(kb + 3) * HID + j], u0);
      a1s[t].u[i] = u0;
    }
    PIN_FRAG32(a1s[t]);
  }
  // ---- layer2 A-frags: fp8(64*W2), own l-tile (w), K=512 in 4 frags ----
  frag32 a2s[4];
#pragma unroll
  for (int f = 0; f < 4; ++f) {
#pragma unroll
    for (int i = 0; i < 8; ++i) {
      const int kb = 128 * f + 32 * q + (i >> 2) * 16 + (i & 3) * 4;
      const float* wp = W2 + 16 * w + lc;
      u32 u0 = cvt2_fp8<false>(64.f * wp[(kb + 0) * LEN],
                               64.f * wp[(kb + 1) * LEN], 0u);
      u0     = cvt2_fp8<true >(64.f * wp[(kb + 2) * LEN],
                               64.f * wp[(kb + 3) * LEN], u0);
      a2s[f].u[i] = u0;
    }
    PIN_FRAG32(a2s[f]);
  }

  // ---- biases in C/D layout (rows j0+r, col lc), x32, PINNED ----
  fvec4 bb1[4], bw1[4];
#pragma unroll
  for (int t = 0; t < 4; ++t) {
    const int j0 = 64 * w + 16 * t + 4 * q;
    f32x4 b1v = *(const f32x4*)(b1 + j0);
    f32x4 w1t = *(const f32x4*)(W1 + 128 * HID + j0);   // time row of W1
#pragma unroll
    for (int r = 0; r < 4; ++r) { bb1[t].f[r] = 32.f * b1v[r]; bw1[t].f[r] = 32.f * w1t[r]; }
    PIN_F4(bb1[t]); PIN_F4(bw1[t]);
  }
  const int l0 = 16 * w + 4 * q;           // owned output rows (tile == w)
  fvec4 nb2;
  {
    f32x4 b2v = *(const f32x4*)(b2 + l0);
#pragma unroll
    for (int r = 0; r < 4; ++r) nb2.f[r] = -0.001f * b2v[r];
    PIN_F4(nb2);
  }

  // loop-invariant LDS addresses
  unsigned char* const xw_p = xqp + w * 256 + lc * 16 + 4 * q;   // x fp8 write
  unsigned char* const hw_p = hqp + w * 1024 + lc * 16 + 4 * q;  // h fp8 write (+t*256)
  const unsigned char* const rd_p = hqp + q * 512 + lc * 16;     // h read base (+f*2048,+256)
  const unsigned char* const xr_p = xqp + q * 512 + lc * 16;     // x read base (+256)

  // ---- x0 = fd[:, 499, :]; fp32 master state (rows l0+r, col batch=lc) ----
  const int obase = (bb + lc) * TROW;
  f32x4 xm = *(const f32x4*)(fd + obase + NSTEPS * LEN + l0);
  *(f32x4*)(out + obase + l0) = xm;                 // out[:, 0, :] = x0
  {
    u32 xw0 = cvt2_fp8<false>(xm[0], xm[1], 0u);
    xw0     = cvt2_fp8<true >(xm[2], xm[3], xw0);
    *(u32*)xw_p = xw0;
  }
  __syncthreads();

  const float DTc = 0.001f;
  const float SD  = 0.031622776601683794f;  // sqrt(DT)
  const float C0  = 0.9995f;                // 1 - 0.5*DT
  const float NS  = -0.001f / 2048.0f;      // -DT / (32*64) descale
  const int   SC1 = 0x7F7F7F7F;             // e8m0 unit scales (2^0) x4 blocks

#pragma unroll 1
  for (int k = 0; k < NSTEPS; ++k) {
    const float tt = DTc * (float)(NSTEPS - k);

    f32x4 eps = *(const f32x4*)(noise + k * LEN + l0);  // prefetch

    // ---- layer 1 (MX fp8, K=128): 2 reads + 4 scaled MFMAs ----
    f32x4 acc1[4];
#pragma unroll
    for (int t = 0; t < 4; ++t)
#pragma unroll
      for (int r = 0; r < 4; ++r)
        acc1[t][r] = __builtin_fmaf(tt, bw1[t].f[r], bb1[t].f[r]);
    {
      frag32 bx;
      bx.h[0] = *(const i32x4*)(xr_p);
      bx.h[1] = *(const i32x4*)(xr_p + 256);
#pragma unroll
      for (int t = 0; t < 4; ++t)
        acc1[t] = __builtin_amdgcn_mfma_scale_f32_16x16x128_f8f6f4(
                    a1s[t].v, bx.v, acc1[t], 0, 0, 0, SC1, 0, SC1);
    }
    // relu -> fp8 pack -> LDS (1 u32 write per t, lane-linear)
#pragma unroll
    for (int t = 0; t < 4; ++t) {
      f32x4 h;
#pragma unroll
      for (int r = 0; r < 4; ++r) h[r] = fmaxf(acc1[t][r], 0.f);
      u32 hw = cvt2_fp8<false>(h[0], h[1], 0u);
      hw     = cvt2_fp8<true >(h[2], h[3], hw);
      *(u32*)(hw_p + t * 256) = hw;
    }
    __syncthreads();   // publish h

    // ---- layer 2 (MX fp8, K=512): 8 reads + 4 scaled MFMAs ----
    f32x4 acc2[2];
    acc2[0] = (f32x4){0.f, 0.f, 0.f, 0.f};
    acc2[1] = (f32x4){0.f, 0.f, 0.f, 0.f};
#pragma unroll
    for (int f = 0; f < 4; ++f) {
      frag32 bh;
      bh.h[0] = *(const i32x4*)(rd_p + f * 2048);
      bh.h[1] = *(const i32x4*)(rd_p + f * 2048 + 256);
      acc2[f & 1] = __builtin_amdgcn_mfma_scale_f32_16x16x128_f8f6f4(
                      a2s[f].v, bh.v, acc2[f & 1], 0, 0, 0, SC1, 0, SC1);
    }

    // ---- Euler–Maruyama update (fp32); score = sc/2048 via NS ----
    f32x4 xn;
#pragma unroll
    for (int r = 0; r < 4; ++r) {
      const float sc = acc2[0][r] + acc2[1][r];
      const float t1 = __builtin_fmaf(SD, eps[r], nb2.f[r]);
      const float t2 = __builtin_fmaf(NS, sc, t1);
      xn[r] = __builtin_fmaf(C0, xm[r], t2);
    }
    xm = xn;
    {
      u32 xw0 = cvt2_fp8<false>(xn[0], xn[1], 0u);
      xw0     = cvt2_fp8<true >(xn[2], xn[3], xw0);
      *(u32*)xw_p = xw0;
    }
    __syncthreads();   // publish x

    // store AFTER the barrier: drains under next step's layer-1
    *(f32x4*)(out + obase + (NSTEPS - k) * LEN + l0) = xn;
  }
}

extern "C" void kernel_launch(void* const* d_in, const int* in_sizes, int n_in,
                              void* d_out, int out_size, void* d_ws, size_t ws_size,
                              hipStream_t stream) {
  const float* fd    = (const float*)d_in[0];
  const float* W1    = (const float*)d_in[1];
  const float* b1    = (const float*)d_in[2];
  const float* W2    = (const float*)d_in[3];
  const float* b2    = (const float*)d_in[4];
  const float* noise = (const float*)d_in[5];
  (void)in_sizes; (void)n_in; (void)out_size; (void)d_ws; (void)ws_size;
  cond_diff_kernel<<<dim3(32), dim3(512), 0, stream>>>(fd, W1, b1, W2, b2, noise,
                                                       (float*)d_out);
}